// Round 1
// baseline (550.454 us; speedup 1.0000x reference)
//
#include <hip/hip_runtime.h>
#include <hip/hip_bf16.h>
#include <stdint.h>

// GlimpseNet fused forward. Pipeline:
//   prep:    foveate (3-scale avg-pooled patches) -> g bf16 [512,9216]
//            W1->bf16, [W3|W4]->B2 bf16 [1152,1152], hw=relu(l@W2^T+b2) -> A2 right cols
//   gemm1:   h = g @ W1bf^T, split-K=16, fp32 partials
//   reduce1: h = relu(sum partials + b1) -> A2 left cols (bf16)
//   gemm2:   out_pre = A2 @ B2^T, split-K=6, fp32 partials
//   reduce2: out = relu(sum partials + b3 + b4) fp32
//
// ws layout (bytes):
//   W1bf : [0,        18874368)   1024*9216 bf16
//   B2   : [18874368, 21528576)   1152*1152 bf16
//   g    : [21528576, 30965760)   512*9216 bf16
//   A2   : [30965760, 32145408)   512*1152 bf16
//   P1   : [32145408, 65699840)   16*512*1024 fp32 (aliased by gemm2 partials 6*512*1152)
// total 65699840 B (~62.7 MB)

typedef __bf16 bf16_t;
typedef __bf16 bf16x8 __attribute__((ext_vector_type(8)));
typedef __bf16 bf16x4 __attribute__((ext_vector_type(4)));
typedef float f32x4 __attribute__((ext_vector_type(4)));

#define OFF_W1BF 0
#define OFF_B2   18874368
#define OFF_G    21528576
#define OFF_A2   30965760
#define OFF_P1   32145408

#define GLOAD_LDS(gp, lp) \
  __builtin_amdgcn_global_load_lds((const __attribute__((address_space(1))) void*)(uintptr_t)(gp), \
                                   (__attribute__((address_space(3))) void*)(uintptr_t)(lp), 16, 0, 0)

// ---------------------------------------------------------------- prep kernel
// blocks [0,1536):     foveate, one block per (b, c)
// blocks [1536,1792):  hw = relu(l @ W2^T + b2) -> A2[:, 1024:1152]
// blocks [1792,2816):  f32->bf16 conversions (W1, and [W3|W4] -> B2)
__global__ __launch_bounds__(256) void prep_kernel(
    const float* __restrict__ x, const float* __restrict__ l,
    const float* __restrict__ W1, const float* __restrict__ W2,
    const float* __restrict__ b2, const float* __restrict__ W3,
    const float* __restrict__ W4,
    bf16_t* __restrict__ g, bf16_t* __restrict__ W1bf,
    bf16_t* __restrict__ B2, bf16_t* __restrict__ A2)
{
  const int blk = blockIdx.x, tid = threadIdx.x;
  if (blk < 1536) {
    const int b = blk / 3, c = blk % 3;
    const float l0 = l[2*b], l1 = l[2*b+1];
    // coords = floor(0.5*((l+1)*[H,W])); fx=coords[:,0] (col), fy=coords[:,1] (row)
    const int fx = (int)floorf(0.5f * ((l0 + 1.0f) * 256.0f));
    const int fy = (int)floorf(0.5f * ((l1 + 1.0f) * 256.0f));
    const float* __restrict__ xc = x + ((size_t)b*3 + (size_t)c) * 65536;
    bf16_t* __restrict__ gb = g + (size_t)b * 9216;
#pragma unroll
    for (int i = 0; i < 12; ++i) {
      const int e  = i*256 + tid;       // 0..3071
      const int n  = i >> 2;            // scale index
      const int k  = 1 << n;
      const int pad = 16 << n;
      const int pe = e & 1023;
      const int py = pe >> 5, px = pe & 31;
      const int r0 = fy + py*k - pad;
      const int c0 = fx + px*k - pad;
      float s = 0.f;
#pragma unroll
      for (int di = 0; di < k; ++di) {
        const int rr = r0 + di;
        if ((unsigned)rr < 256u) {
          const float* __restrict__ xr = xc + rr*256;
#pragma unroll
          for (int dj = 0; dj < k; ++dj) {
            const int cc = c0 + dj;
            if ((unsigned)cc < 256u) s += xr[cc];
          }
        }
      }
      s *= (1.0f / (float)(k*k));
      gb[((n*3 + c) << 10) + pe] = (bf16_t)s;
    }
  } else if (blk < 1792) {
    const int u = (blk - 1536)*256 + tid;   // 0..65535
    const int b = u >> 7, j = u & 127;
    float v = l[2*b]*W2[2*j] + l[2*b+1]*W2[2*j+1] + b2[j];
    v = fmaxf(v, 0.f);
    A2[(size_t)b*1152 + 1024 + j] = (bf16_t)v;
  } else {
    const int W1_4  = 9437184/4;          // 2359296
    const int TOT_4 = W1_4 + 1327104/4;   // 2691072
    const int stride = 1024*256;
    for (int t = (blk - 1792)*256 + tid; t < TOT_4; t += stride) {
      if (t < W1_4) {
        f32x4 v = *(const f32x4*)(W1 + 4*(size_t)t);
        bf16x4 o;
#pragma unroll
        for (int q = 0; q < 4; ++q) o[q] = (bf16_t)v[q];
        *(bf16x4*)(W1bf + 4*(size_t)t) = o;
      } else {
        const int e  = (t - W1_4) * 4;
        const int n  = e / 1152;
        const int kk = e - n*1152;
        f32x4 v;
        if (kk < 1024) v = *(const f32x4*)(W3 + (size_t)n*1024 + kk);
        else           v = *(const f32x4*)(W4 + (size_t)n*128 + (kk - 1024));
        bf16x4 o;
#pragma unroll
        for (int q = 0; q < 4; ++q) o[q] = (bf16_t)v[q];
        *(bf16x4*)(B2 + (size_t)n*1152 + kk) = o;
      }
    }
  }
}

// ---------------------------------------------------------- split-K bf16 GEMM
// C_partial[s] = A[bm tile] @ B[bn tile]^T over K-chunk s.
// A: [M,K] bf16 row-major, B: [N,K] bf16 row-major, P: [KSPLIT,M,N] fp32.
// 128x128 tile, 256 thr = 4 waves (2x2), each wave 64x64 via 4x4 mfma 16x16x32.
template<int KSPLIT>
__global__ __launch_bounds__(256, 2) void gemm_bt(
    const bf16_t* __restrict__ A, int lda,
    const bf16_t* __restrict__ B, int ldb,
    float* __restrict__ P, int M, int N, int K)
{
  __shared__ bf16_t As[128*32];
  __shared__ bf16_t Bs[128*32];
  const int tm = M >> 7, tn = N >> 7;
  const int bid = blockIdx.x;
  const int s  = bid / (tm*tn);
  const int r  = bid - s*(tm*tn);
  const int bm = r % tm, bn = r / tm;
  const int tid = threadIdx.x;
  const int chunk = K / KSPLIT;
  const int nk = chunk >> 5;
  const int k0 = s * chunk;

  const int lane = tid & 63;
  const int wave = tid >> 6;
  const int wm = wave & 1, wn = wave >> 1;
  const int lane16 = lane & 15, quad = lane >> 4;

  // staging: each thread covers 16B (8 bf16); 64 rows per issue, 2 issues per tile
  const int arow = tid >> 2;
  const int acol = (tid & 3) * 8;
  const bf16_t* ga0 = A + (size_t)(bm*128 + arow)*lda + k0 + acol;
  const bf16_t* ga1 = ga0 + (size_t)64*lda;
  const bf16_t* gb0 = B + (size_t)(bn*128 + arow)*ldb + k0 + acol;
  const bf16_t* gb1 = gb0 + (size_t)64*ldb;
  bf16_t* lA0 = As + tid*8;
  bf16_t* lA1 = As + 2048 + tid*8;
  bf16_t* lB0 = Bs + tid*8;
  bf16_t* lB1 = Bs + 2048 + tid*8;

  const bf16_t* asp = As + (wm*64 + lane16)*32 + quad*8;
  const bf16_t* bsp = Bs + (wn*64 + lane16)*32 + quad*8;

  f32x4 acc[4][4] = {};

  for (int kt = 0; kt < nk; ++kt) {
    GLOAD_LDS(ga0, lA0);
    GLOAD_LDS(ga1, lA1);
    GLOAD_LDS(gb0, lB0);
    GLOAD_LDS(gb1, lB1);
    __syncthreads();   // drain vmcnt -> LDS tile ready
    bf16x8 af[4], bf[4];
#pragma unroll
    for (int mf = 0; mf < 4; ++mf) af[mf] = *(const bf16x8*)(asp + mf*512);
#pragma unroll
    for (int nf = 0; nf < 4; ++nf) bf[nf] = *(const bf16x8*)(bsp + nf*512);
#pragma unroll
    for (int mf = 0; mf < 4; ++mf)
#pragma unroll
      for (int nf = 0; nf < 4; ++nf)
        acc[mf][nf] = __builtin_amdgcn_mfma_f32_16x16x32_bf16(af[mf], bf[nf], acc[mf][nf], 0, 0, 0);
    __syncthreads();   // all reads done before next overwrite
    ga0 += 32; ga1 += 32; gb0 += 32; gb1 += 32;
  }

  float* pout = P + (size_t)s*M*N + (size_t)(bm*128 + wm*64)*N + (bn*128 + wn*64);
#pragma unroll
  for (int mf = 0; mf < 4; ++mf)
#pragma unroll
    for (int nf = 0; nf < 4; ++nf)
#pragma unroll
      for (int r2 = 0; r2 < 4; ++r2) {
        const int m = mf*16 + quad*4 + r2;   // C/D: row = quad*4 + reg
        const int n = nf*16 + lane16;        //      col = lane & 15
        pout[(size_t)m*N + n] = acc[mf][nf][r2];
      }
}

// ------------------------------------------------------------------- reduces
__global__ __launch_bounds__(256) void reduce1_kernel(
    const float* __restrict__ P, const float* __restrict__ b1,
    bf16_t* __restrict__ A2)
{
  const int t = blockIdx.x*256 + threadIdx.x;  // 131072 threads
  const int j4 = t << 2;
  const int b = j4 >> 10;
  const int j = j4 & 1023;
  f32x4 s = {};
#pragma unroll
  for (int ss = 0; ss < 16; ++ss)
    s += *(const f32x4*)(P + ((size_t)(ss*512 + b) << 10) + j);
  f32x4 bb = *(const f32x4*)(b1 + j);
  bf16x4 o;
#pragma unroll
  for (int q = 0; q < 4; ++q) o[q] = (bf16_t)fmaxf(s[q] + bb[q], 0.f);
  *(bf16x4*)(A2 + (size_t)b*1152 + j) = o;
}

__global__ __launch_bounds__(256) void reduce2_kernel(
    const float* __restrict__ P, const float* __restrict__ b3,
    const float* __restrict__ b4, float* __restrict__ out)
{
  const int t = blockIdx.x*256 + threadIdx.x;  // 147456 threads
  const int j4 = t << 2;
  const int b = j4 / 1152;
  const int j = j4 - b*1152;
  f32x4 s = {};
#pragma unroll
  for (int ss = 0; ss < 6; ++ss)
    s += *(const f32x4*)(P + ((size_t)ss*512 + (size_t)b)*1152 + j);
  f32x4 v3 = *(const f32x4*)(b3 + j);
  f32x4 v4 = *(const f32x4*)(b4 + j);
  f32x4 o;
#pragma unroll
  for (int q = 0; q < 4; ++q) o[q] = fmaxf(s[q] + v3[q] + v4[q], 0.f);
  *(f32x4*)(out + (size_t)b*1152 + j) = o;
}

// -------------------------------------------------------------------- launch
extern "C" void kernel_launch(void* const* d_in, const int* in_sizes, int n_in,
                              void* d_out, int out_size, void* d_ws, size_t ws_size,
                              hipStream_t stream) {
  const float* x  = (const float*)d_in[0];
  const float* l  = (const float*)d_in[1];
  const float* W1 = (const float*)d_in[2];
  const float* b1 = (const float*)d_in[3];
  const float* W2 = (const float*)d_in[4];
  const float* b2 = (const float*)d_in[5];
  const float* W3 = (const float*)d_in[6];
  const float* b3 = (const float*)d_in[7];
  const float* W4 = (const float*)d_in[8];
  const float* b4 = (const float*)d_in[9];
  float* out = (float*)d_out;
  char* ws = (char*)d_ws;
  bf16_t* W1bf = (bf16_t*)(ws + OFF_W1BF);
  bf16_t* B2   = (bf16_t*)(ws + OFF_B2);
  bf16_t* g    = (bf16_t*)(ws + OFF_G);
  bf16_t* A2   = (bf16_t*)(ws + OFF_A2);
  float*  P1   = (float*)(ws + OFF_P1);

  prep_kernel<<<2816, 256, 0, stream>>>(x, l, W1, W2, b2, W3, W4, g, W1bf, B2, A2);
  // h partials: M=512, N=1024, K=9216, split 16 -> 512 blocks
  gemm_bt<16><<<4*8*16, 256, 0, stream>>>(g, 9216, W1bf, 9216, P1, 512, 1024, 9216);
  reduce1_kernel<<<512, 256, 0, stream>>>(P1, b1, A2);
  // out partials: M=512, N=1152, K=1152, split 6 -> 216 blocks
  gemm_bt<6><<<4*9*6, 256, 0, stream>>>(A2, 1152, B2, 1152, P1, 512, 1152, 1152);
  reduce2_kernel<<<576, 256, 0, stream>>>(P1, b3, b4, out);
}

// Round 2
// 546.051 us; speedup vs baseline: 1.0081x; 1.0081x over previous
//
#include <hip/hip_runtime.h>
#include <hip/hip_bf16.h>
#include <stdint.h>

// GlimpseNet fused forward. Pipeline:
//   prep:    foveate (3-scale avg-pooled patches) -> g bf16 [512,9216]
//            W1->bf16, [W3|W4]->B2 bf16 [1152,1152], hw=relu(l@W2^T+b2) -> A2 right cols
//   gemm1:   h = g @ W1bf^T, split-K=16, fp32 partials
//   reduce1: h = relu(sum partials + b1) -> A2 left cols (bf16)
//   gemm2:   out_pre = A2 @ B2^T, split-K=6, fp32 partials
//   reduce2: out = relu(sum partials + b3 + b4) fp32
//
// R1->R2: gemm stages two BK=32 sub-tiles per barrier pair (32 MFMA/wave per
// barrier, half the syncs); prep conversion writes 16B (bf16x8).

typedef __bf16 bf16_t;
typedef __bf16 bf16x8 __attribute__((ext_vector_type(8)));
typedef __bf16 bf16x4 __attribute__((ext_vector_type(4)));
typedef float f32x4 __attribute__((ext_vector_type(4)));

#define OFF_W1BF 0
#define OFF_B2   18874368
#define OFF_G    21528576
#define OFF_A2   30965760
#define OFF_P1   32145408

#define GLOAD_LDS(gp, lp) \
  __builtin_amdgcn_global_load_lds((const __attribute__((address_space(1))) void*)(uintptr_t)(gp), \
                                   (__attribute__((address_space(3))) void*)(uintptr_t)(lp), 16, 0, 0)

// ---------------------------------------------------------------- prep kernel
// blocks [0,1536):     foveate, one block per (b, c)
// blocks [1536,1792):  hw = relu(l @ W2^T + b2) -> A2[:, 1024:1152]
// blocks [1792,2816):  f32->bf16 conversions (W1, and [W3|W4] -> B2), 16B I/O
__global__ __launch_bounds__(256) void prep_kernel(
    const float* __restrict__ x, const float* __restrict__ l,
    const float* __restrict__ W1, const float* __restrict__ W2,
    const float* __restrict__ b2, const float* __restrict__ W3,
    const float* __restrict__ W4,
    bf16_t* __restrict__ g, bf16_t* __restrict__ W1bf,
    bf16_t* __restrict__ B2, bf16_t* __restrict__ A2)
{
  const int blk = blockIdx.x, tid = threadIdx.x;
  if (blk < 1536) {
    const int b = blk / 3, c = blk % 3;
    const float l0 = l[2*b], l1 = l[2*b+1];
    // coords = floor(0.5*((l+1)*[H,W])); fx=coords[:,0] (col), fy=coords[:,1] (row)
    const int fx = (int)floorf(0.5f * ((l0 + 1.0f) * 256.0f));
    const int fy = (int)floorf(0.5f * ((l1 + 1.0f) * 256.0f));
    const float* __restrict__ xc = x + ((size_t)b*3 + (size_t)c) * 65536;
    bf16_t* __restrict__ gb = g + (size_t)b * 9216;
#pragma unroll
    for (int i = 0; i < 12; ++i) {
      const int e  = i*256 + tid;       // 0..3071
      const int n  = i >> 2;            // scale index
      const int k  = 1 << n;
      const int pad = 16 << n;
      const int pe = e & 1023;
      const int py = pe >> 5, px = pe & 31;
      const int r0 = fy + py*k - pad;
      const int c0 = fx + px*k - pad;
      float s = 0.f;
#pragma unroll
      for (int di = 0; di < k; ++di) {
        const int rr = r0 + di;
        if ((unsigned)rr < 256u) {
          const float* __restrict__ xr = xc + rr*256;
#pragma unroll
          for (int dj = 0; dj < k; ++dj) {
            const int cc = c0 + dj;
            if ((unsigned)cc < 256u) s += xr[cc];
          }
        }
      }
      s *= (1.0f / (float)(k*k));
      gb[((n*3 + c) << 10) + pe] = (bf16_t)s;
    }
  } else if (blk < 1792) {
    const int u = (blk - 1536)*256 + tid;   // 0..65535
    const int b = u >> 7, j = u & 127;
    float v = l[2*b]*W2[2*j] + l[2*b+1]*W2[2*j+1] + b2[j];
    v = fmaxf(v, 0.f);
    A2[(size_t)b*1152 + 1024 + j] = (bf16_t)v;
  } else {
    // 8-element (16B-out) groups
    const int W1_8  = 9437184/8;          // 1179648
    const int TOT_8 = W1_8 + 1327104/8;   // 1345536
    const int stride = 1024*256;
    for (int t = (blk - 1792)*256 + tid; t < TOT_8; t += stride) {
      f32x4 v0, v1;
      bf16_t* dst;
      if (t < W1_8) {
        const float* src = W1 + 8*(size_t)t;
        v0 = *(const f32x4*)src; v1 = *(const f32x4*)(src + 4);
        dst = W1bf + 8*(size_t)t;
      } else {
        const int e  = (t - W1_8) * 8;
        const int n  = e / 1152;
        const int kk = e - n*1152;        // multiple of 8; never straddles 1024
        const float* src = (kk < 1024) ? (W3 + (size_t)n*1024 + kk)
                                       : (W4 + (size_t)n*128 + (kk - 1024));
        v0 = *(const f32x4*)src; v1 = *(const f32x4*)(src + 4);
        dst = B2 + (size_t)n*1152 + kk;
      }
      bf16x8 o;
#pragma unroll
      for (int q = 0; q < 4; ++q) { o[q] = (bf16_t)v0[q]; o[q+4] = (bf16_t)v1[q]; }
      *(bf16x8*)dst = o;
    }
  }
}

// ---------------------------------------------------------- split-K bf16 GEMM
// C_partial[s] = A[bm tile] @ B[bn tile]^T over K-chunk s.
// A: [M,K] bf16 row-major, B: [N,K] bf16 row-major, P: [KSPLIT,M,N] fp32.
// 128x128 tile, 256 thr = 4 waves (2x2), wave 64x64 via 4x4 mfma 16x16x32.
// Two BK=32 sub-tiles staged per barrier pair (BK=64 effective).
// chunk = K/KSPLIT must be a multiple of 64.
template<int KSPLIT>
__global__ __launch_bounds__(256, 2) void gemm_bt(
    const bf16_t* __restrict__ A, int lda,
    const bf16_t* __restrict__ B, int ldb,
    float* __restrict__ P, int M, int N, int K)
{
  __shared__ bf16_t As[2*128*32];   // [half][row][32]
  __shared__ bf16_t Bs[2*128*32];
  const int tm = M >> 7, tn = N >> 7;
  const int bid = blockIdx.x;
  const int s  = bid / (tm*tn);
  const int r  = bid - s*(tm*tn);
  const int bm = r % tm, bn = r / tm;
  const int tid = threadIdx.x;
  const int chunk = K / KSPLIT;
  const int nk = chunk >> 6;        // 64 K per iteration
  const int k0 = s * chunk;

  const int lane = tid & 63;
  const int wave = tid >> 6;
  const int wm = wave & 1, wn = wave >> 1;
  const int lane16 = lane & 15, quad = lane >> 4;

  // staging: each thread covers 16B (8 bf16); 64 rows per issue
  const int arow = tid >> 2;
  const int acol = (tid & 3) * 8;
  const bf16_t* ga0 = A + (size_t)(bm*128 + arow)*lda + k0 + acol;
  const bf16_t* ga1 = ga0 + (size_t)64*lda;
  const bf16_t* gb0 = B + (size_t)(bn*128 + arow)*ldb + k0 + acol;
  const bf16_t* gb1 = gb0 + (size_t)64*ldb;
  bf16_t* lA0 = As + tid*8;         // half0 rows 0-63
  bf16_t* lA1 = As + 2048 + tid*8;  // half0 rows 64-127
  bf16_t* lA2 = As + 4096 + tid*8;  // half1 rows 0-63
  bf16_t* lA3 = As + 6144 + tid*8;  // half1 rows 64-127
  bf16_t* lB0 = Bs + tid*8;
  bf16_t* lB1 = Bs + 2048 + tid*8;
  bf16_t* lB2 = Bs + 4096 + tid*8;
  bf16_t* lB3 = Bs + 6144 + tid*8;

  const bf16_t* asp = As + (wm*64 + lane16)*32 + quad*8;
  const bf16_t* bsp = Bs + (wn*64 + lane16)*32 + quad*8;

  f32x4 acc[4][4] = {};

  for (int kt = 0; kt < nk; ++kt) {
    GLOAD_LDS(ga0, lA0);
    GLOAD_LDS(ga1, lA1);
    GLOAD_LDS(ga0 + 32, lA2);
    GLOAD_LDS(ga1 + 32, lA3);
    GLOAD_LDS(gb0, lB0);
    GLOAD_LDS(gb1, lB1);
    GLOAD_LDS(gb0 + 32, lB2);
    GLOAD_LDS(gb1 + 32, lB3);
    __syncthreads();   // drain vmcnt -> both LDS sub-tiles ready
#pragma unroll
    for (int h = 0; h < 2; ++h) {
      bf16x8 af[4], bf[4];
#pragma unroll
      for (int mf = 0; mf < 4; ++mf) af[mf] = *(const bf16x8*)(asp + h*4096 + mf*512);
#pragma unroll
      for (int nf = 0; nf < 4; ++nf) bf[nf] = *(const bf16x8*)(bsp + h*4096 + nf*512);
#pragma unroll
      for (int mf = 0; mf < 4; ++mf)
#pragma unroll
        for (int nf = 0; nf < 4; ++nf)
          acc[mf][nf] = __builtin_amdgcn_mfma_f32_16x16x32_bf16(af[mf], bf[nf], acc[mf][nf], 0, 0, 0);
    }
    __syncthreads();   // all reads done before next overwrite
    ga0 += 64; ga1 += 64; gb0 += 64; gb1 += 64;
  }

  float* pout = P + (size_t)s*M*N + (size_t)(bm*128 + wm*64)*N + (bn*128 + wn*64);
#pragma unroll
  for (int mf = 0; mf < 4; ++mf)
#pragma unroll
    for (int nf = 0; nf < 4; ++nf)
#pragma unroll
      for (int r2 = 0; r2 < 4; ++r2) {
        const int m = mf*16 + quad*4 + r2;   // C/D: row = quad*4 + reg
        const int n = nf*16 + lane16;        //      col = lane & 15
        pout[(size_t)m*N + n] = acc[mf][nf][r2];
      }
}

// ------------------------------------------------------------------- reduces
__global__ __launch_bounds__(256) void reduce1_kernel(
    const float* __restrict__ P, const float* __restrict__ b1,
    bf16_t* __restrict__ A2)
{
  const int t = blockIdx.x*256 + threadIdx.x;  // 131072 threads
  const int j4 = t << 2;
  const int b = j4 >> 10;
  const int j = j4 & 1023;
  f32x4 s = {};
#pragma unroll
  for (int ss = 0; ss < 16; ++ss)
    s += *(const f32x4*)(P + ((size_t)(ss*512 + b) << 10) + j);
  f32x4 bb = *(const f32x4*)(b1 + j);
  bf16x4 o;
#pragma unroll
  for (int q = 0; q < 4; ++q) o[q] = (bf16_t)fmaxf(s[q] + bb[q], 0.f);
  *(bf16x4*)(A2 + (size_t)b*1152 + j) = o;
}

__global__ __launch_bounds__(256) void reduce2_kernel(
    const float* __restrict__ P, const float* __restrict__ b3,
    const float* __restrict__ b4, float* __restrict__ out)
{
  const int t = blockIdx.x*256 + threadIdx.x;  // 147456 threads
  const int j4 = t << 2;
  const int b = j4 / 1152;
  const int j = j4 - b*1152;
  f32x4 s = {};
#pragma unroll
  for (int ss = 0; ss < 6; ++ss)
    s += *(const f32x4*)(P + ((size_t)ss*512 + (size_t)b)*1152 + j);
  f32x4 v3 = *(const f32x4*)(b3 + j);
  f32x4 v4 = *(const f32x4*)(b4 + j);
  f32x4 o;
#pragma unroll
  for (int q = 0; q < 4; ++q) o[q] = fmaxf(s[q] + v3[q] + v4[q], 0.f);
  *(f32x4*)(out + (size_t)b*1152 + j) = o;
}

// -------------------------------------------------------------------- launch
extern "C" void kernel_launch(void* const* d_in, const int* in_sizes, int n_in,
                              void* d_out, int out_size, void* d_ws, size_t ws_size,
                              hipStream_t stream) {
  const float* x  = (const float*)d_in[0];
  const float* l  = (const float*)d_in[1];
  const float* W1 = (const float*)d_in[2];
  const float* b1 = (const float*)d_in[3];
  const float* W2 = (const float*)d_in[4];
  const float* b2 = (const float*)d_in[5];
  const float* W3 = (const float*)d_in[6];
  const float* b3 = (const float*)d_in[7];
  const float* W4 = (const float*)d_in[8];
  const float* b4 = (const float*)d_in[9];
  float* out = (float*)d_out;
  char* ws = (char*)d_ws;
  bf16_t* W1bf = (bf16_t*)(ws + OFF_W1BF);
  bf16_t* B2   = (bf16_t*)(ws + OFF_B2);
  bf16_t* g    = (bf16_t*)(ws + OFF_G);
  bf16_t* A2   = (bf16_t*)(ws + OFF_A2);
  float*  P1   = (float*)(ws + OFF_P1);

  prep_kernel<<<2816, 256, 0, stream>>>(x, l, W1, W2, b2, W3, W4, g, W1bf, B2, A2);
  // h partials: M=512, N=1024, K=9216, split 16 -> 512 blocks, chunk 576 (9 iters)
  gemm_bt<16><<<4*8*16, 256, 0, stream>>>(g, 9216, W1bf, 9216, P1, 512, 1024, 9216);
  reduce1_kernel<<<512, 256, 0, stream>>>(P1, b1, A2);
  // out partials: M=512, N=1152, K=1152, split 6 -> 216 blocks, chunk 192 (3 iters)
  gemm_bt<6><<<4*9*6, 256, 0, stream>>>(A2, 1152, B2, 1152, P1, 512, 1152, 1152);
  reduce2_kernel<<<576, 256, 0, stream>>>(P1, b3, b4, out);
}

// Round 4
// 540.299 us; speedup vs baseline: 1.0188x; 1.0106x over previous
//
#include <hip/hip_runtime.h>
#include <hip/hip_bf16.h>
#include <stdint.h>

// GlimpseNet fused forward. Pipeline:
//   prep:    foveate (3-scale avg-pooled patches) -> g bf16 [512,9216]
//            W1->bf16, [W3|W4]->B2 bf16 [1152,1152], hw=relu(l@W2^T+b2) -> A2 right cols
//   gemm1:   h = g @ W1bf^T, split-K=16, fp32 partials
//   reduce1: h = relu(sum partials + b1) -> A2 left cols (bf16)
//   gemm2:   out_pre = A2 @ B2^T, split-K=6, fp32 partials
//   reduce2: out = relu(sum partials + b3 + b4) fp32
//
// R3->R4: fix foveate pool factors. Patch sizes 32/64/128 -> pool k=1/2/4
// (R3 wrongly used 4/16 with divisors 1/16,1/256). Vectorization kept:
// window col-start ≡ fx (mod 4) block-uniform; clamp window to image, read
// the 4-aligned covering span, mask with 0/1 vectors.

typedef __bf16 bf16_t;
typedef __bf16 bf16x8 __attribute__((ext_vector_type(8)));
typedef __bf16 bf16x4 __attribute__((ext_vector_type(4)));
typedef float f32x4 __attribute__((ext_vector_type(4)));

#define OFF_W1BF 0
#define OFF_B2   18874368
#define OFF_G    21528576
#define OFF_A2   30965760
#define OFF_P1   32145408

#define GLOAD_LDS(gp, lp) \
  __builtin_amdgcn_global_load_lds((const __attribute__((address_space(1))) void*)(uintptr_t)(gp), \
                                   (__attribute__((address_space(3))) void*)(uintptr_t)(lp), 16, 0, 0)

// ---------------------------------------------------------------- prep kernel
// blocks [0,1536):     foveate, one block per (b, ch)
// blocks [1536,1792):  hw = relu(l @ W2^T + b2) -> A2[:, 1024:1152]
// blocks [1792,2816):  f32->bf16 conversions (W1, and [W3|W4] -> B2), 16B I/O
__global__ __launch_bounds__(256) void prep_kernel(
    const float* __restrict__ x, const float* __restrict__ l,
    const float* __restrict__ W1, const float* __restrict__ W2,
    const float* __restrict__ b2, const float* __restrict__ W3,
    const float* __restrict__ W4,
    bf16_t* __restrict__ g, bf16_t* __restrict__ W1bf,
    bf16_t* __restrict__ B2, bf16_t* __restrict__ A2)
{
  const int blk = blockIdx.x, tid = threadIdx.x;
  if (blk < 1536) {
    const int b = blk / 3, ch = blk % 3;
    const float l0 = l[2*b], l1 = l[2*b+1];
    // coords = floor(0.5*((l+1)*[H,W])); fx = col, fy = row
    const int fx = (int)floorf(0.5f * ((l0 + 1.0f) * 256.0f));
    const int fy = (int)floorf(0.5f * ((l1 + 1.0f) * 256.0f));
    const float* __restrict__ xc = x + ((size_t)b*3 + (size_t)ch) * 65536;
    bf16_t* __restrict__ gb = g + (size_t)b * 9216;

    // ---- scale 0 (patch 32, k=1): direct coalesced loads
#pragma unroll
    for (int i = 0; i < 4; ++i) {
      const int pe = i*256 + tid;
      const int py = pe >> 5, px = pe & 31;
      const int rr = fy + py - 16, cc = fx + px - 16;
      float s = 0.f;
      if ((unsigned)rr < 256u && (unsigned)cc < 256u) s = xc[rr*256 + cc];
      gb[(ch << 10) + pe] = (bf16_t)s;
    }

    // ---- scale 1 (patch 64, k=2, pad 32): 2 rows x <=2 float4
#pragma unroll
    for (int i = 0; i < 4; ++i) {
      const int pe = i*256 + tid;
      const int py = pe >> 5, px = pe & 31;
      const int r0 = fy + 2*py - 32;
      const int c0 = fx + 2*px - 32;
      const int cs = c0 < 0 ? 0 : c0;
      const int ce = (c0 + 2) > 256 ? 256 : (c0 + 2);
      float s = 0.f;
      if (cs < ce) {
        const int cal = cs & ~3;
        const int nj  = ((ce - cal) + 3) >> 2;   // 1..2
        f32x4 m[2];
#pragma unroll
        for (int j = 0; j < 2; ++j)
#pragma unroll
          for (int q = 0; q < 4; ++q) {
            const int col = cal + 4*j + q;
            m[j][q] = (col >= cs && col < ce) ? 1.f : 0.f;
          }
        f32x4 sv = {};
#pragma unroll
        for (int di = 0; di < 2; ++di) {
          const int rr = r0 + di;
          if ((unsigned)rr < 256u) {
            const float* __restrict__ xr = xc + rr*256 + cal;
#pragma unroll
            for (int j = 0; j < 2; ++j)
              if (j < nj) sv += (*(const f32x4*)(xr + 4*j)) * m[j];
          }
        }
        s = (sv[0] + sv[1] + sv[2] + sv[3]) * 0.25f;
      }
      gb[((3 + ch) << 10) + pe] = (bf16_t)s;
    }

    // ---- scale 2 (patch 128, k=4, pad 64): 4 rows x <=2 float4
#pragma unroll
    for (int i = 0; i < 4; ++i) {
      const int pe = i*256 + tid;
      const int py = pe >> 5, px = pe & 31;
      const int r0 = fy + 4*py - 64;
      const int c0 = fx + 4*px - 64;
      const int cs = c0 < 0 ? 0 : c0;
      const int ce = (c0 + 4) > 256 ? 256 : (c0 + 4);
      float s = 0.f;
      if (cs < ce && r0 < 256 && r0 + 4 > 0) {
        const int cal = cs & ~3;
        const int nj  = ((ce - cal) + 3) >> 2;   // 1..2
        f32x4 m[2];
#pragma unroll
        for (int j = 0; j < 2; ++j)
#pragma unroll
          for (int q = 0; q < 4; ++q) {
            const int col = cal + 4*j + q;
            m[j][q] = (col >= cs && col < ce) ? 1.f : 0.f;
          }
        f32x4 sv = {};
#pragma unroll
        for (int di = 0; di < 4; ++di) {
          const int rr = r0 + di;
          if ((unsigned)rr < 256u) {
            const float* __restrict__ xr = xc + rr*256 + cal;
#pragma unroll
            for (int j = 0; j < 2; ++j)
              if (j < nj) sv += (*(const f32x4*)(xr + 4*j)) * m[j];
          }
        }
        s = (sv[0] + sv[1] + sv[2] + sv[3]) * 0.0625f;
      }
      gb[((6 + ch) << 10) + pe] = (bf16_t)s;
    }
  } else if (blk < 1792) {
    const int u = (blk - 1536)*256 + tid;   // 0..65535
    const int b = u >> 7, j = u & 127;
    float v = l[2*b]*W2[2*j] + l[2*b+1]*W2[2*j+1] + b2[j];
    v = fmaxf(v, 0.f);
    A2[(size_t)b*1152 + 1024 + j] = (bf16_t)v;
  } else {
    // 8-element (16B-out) groups
    const int W1_8  = 9437184/8;          // 1179648
    const int TOT_8 = W1_8 + 1327104/8;   // 1345536
    const int stride = 1024*256;
    for (int t = (blk - 1792)*256 + tid; t < TOT_8; t += stride) {
      f32x4 v0, v1;
      bf16_t* dst;
      if (t < W1_8) {
        const float* src = W1 + 8*(size_t)t;
        v0 = *(const f32x4*)src; v1 = *(const f32x4*)(src + 4);
        dst = W1bf + 8*(size_t)t;
      } else {
        const int e  = (t - W1_8) * 8;
        const int n  = e / 1152;
        const int kk = e - n*1152;        // multiple of 8; never straddles 1024
        const float* src = (kk < 1024) ? (W3 + (size_t)n*1024 + kk)
                                       : (W4 + (size_t)n*128 + (kk - 1024));
        v0 = *(const f32x4*)src; v1 = *(const f32x4*)(src + 4);
        dst = B2 + (size_t)n*1152 + kk;
      }
      bf16x8 o;
#pragma unroll
      for (int q = 0; q < 4; ++q) { o[q] = (bf16_t)v0[q]; o[q+4] = (bf16_t)v1[q]; }
      *(bf16x8*)dst = o;
    }
  }
}

// ---------------------------------------------------------- split-K bf16 GEMM
// C_partial[s] = A[bm tile] @ B[bn tile]^T over K-chunk s.
// A: [M,K] bf16 row-major, B: [N,K] bf16 row-major, P: [KSPLIT,M,N] fp32.
// 128x128 tile, 256 thr = 4 waves (2x2), wave 64x64 via 4x4 mfma 16x16x32.
// Two BK=32 sub-tiles staged per barrier pair (BK=64 effective).
// chunk = K/KSPLIT must be a multiple of 64.
template<int KSPLIT>
__global__ __launch_bounds__(256, 2) void gemm_bt(
    const bf16_t* __restrict__ A, int lda,
    const bf16_t* __restrict__ B, int ldb,
    float* __restrict__ P, int M, int N, int K)
{
  __shared__ bf16_t As[2*128*32];   // [half][row][32]
  __shared__ bf16_t Bs[2*128*32];
  const int tm = M >> 7, tn = N >> 7;
  const int bid = blockIdx.x;
  const int s  = bid / (tm*tn);
  const int r  = bid - s*(tm*tn);
  const int bm = r % tm, bn = r / tm;
  const int tid = threadIdx.x;
  const int chunk = K / KSPLIT;
  const int nk = chunk >> 6;        // 64 K per iteration
  const int k0 = s * chunk;

  const int lane = tid & 63;
  const int wave = tid >> 6;
  const int wm = wave & 1, wn = wave >> 1;
  const int lane16 = lane & 15, quad = lane >> 4;

  // staging: each thread covers 16B (8 bf16); 64 rows per issue
  const int arow = tid >> 2;
  const int acol = (tid & 3) * 8;
  const bf16_t* ga0 = A + (size_t)(bm*128 + arow)*lda + k0 + acol;
  const bf16_t* ga1 = ga0 + (size_t)64*lda;
  const bf16_t* gb0 = B + (size_t)(bn*128 + arow)*ldb + k0 + acol;
  const bf16_t* gb1 = gb0 + (size_t)64*ldb;
  bf16_t* lA0 = As + tid*8;         // half0 rows 0-63
  bf16_t* lA1 = As + 2048 + tid*8;  // half0 rows 64-127
  bf16_t* lA2 = As + 4096 + tid*8;  // half1 rows 0-63
  bf16_t* lA3 = As + 6144 + tid*8;  // half1 rows 64-127
  bf16_t* lB0 = Bs + tid*8;
  bf16_t* lB1 = Bs + 2048 + tid*8;
  bf16_t* lB2 = Bs + 4096 + tid*8;
  bf16_t* lB3 = Bs + 6144 + tid*8;

  const bf16_t* asp = As + (wm*64 + lane16)*32 + quad*8;
  const bf16_t* bsp = Bs + (wn*64 + lane16)*32 + quad*8;

  f32x4 acc[4][4] = {};

  for (int kt = 0; kt < nk; ++kt) {
    GLOAD_LDS(ga0, lA0);
    GLOAD_LDS(ga1, lA1);
    GLOAD_LDS(ga0 + 32, lA2);
    GLOAD_LDS(ga1 + 32, lA3);
    GLOAD_LDS(gb0, lB0);
    GLOAD_LDS(gb1, lB1);
    GLOAD_LDS(gb0 + 32, lB2);
    GLOAD_LDS(gb1 + 32, lB3);
    __syncthreads();   // drain vmcnt -> both LDS sub-tiles ready
#pragma unroll
    for (int h = 0; h < 2; ++h) {
      bf16x8 af[4], bf[4];
#pragma unroll
      for (int mf = 0; mf < 4; ++mf) af[mf] = *(const bf16x8*)(asp + h*4096 + mf*512);
#pragma unroll
      for (int nf = 0; nf < 4; ++nf) bf[nf] = *(const bf16x8*)(bsp + h*4096 + nf*512);
#pragma unroll
      for (int mf = 0; mf < 4; ++mf)
#pragma unroll
        for (int nf = 0; nf < 4; ++nf)
          acc[mf][nf] = __builtin_amdgcn_mfma_f32_16x16x32_bf16(af[mf], bf[nf], acc[mf][nf], 0, 0, 0);
    }
    __syncthreads();   // all reads done before next overwrite
    ga0 += 64; ga1 += 64; gb0 += 64; gb1 += 64;
  }

  float* pout = P + (size_t)s*M*N + (size_t)(bm*128 + wm*64)*N + (bn*128 + wn*64);
#pragma unroll
  for (int mf = 0; mf < 4; ++mf)
#pragma unroll
    for (int nf = 0; nf < 4; ++nf)
#pragma unroll
      for (int r2 = 0; r2 < 4; ++r2) {
        const int m = mf*16 + quad*4 + r2;   // C/D: row = quad*4 + reg
        const int n = nf*16 + lane16;        //      col = lane & 15
        pout[(size_t)m*N + n] = acc[mf][nf][r2];
      }
}

// ------------------------------------------------------------------- reduces
__global__ __launch_bounds__(256) void reduce1_kernel(
    const float* __restrict__ P, const float* __restrict__ b1,
    bf16_t* __restrict__ A2)
{
  const int t = blockIdx.x*256 + threadIdx.x;  // 131072 threads
  const int j4 = t << 2;
  const int b = j4 >> 10;
  const int j = j4 & 1023;
  f32x4 s = {};
#pragma unroll
  for (int ss = 0; ss < 16; ++ss)
    s += *(const f32x4*)(P + ((size_t)(ss*512 + b) << 10) + j);
  f32x4 bb = *(const f32x4*)(b1 + j);
  bf16x4 o;
#pragma unroll
  for (int q = 0; q < 4; ++q) o[q] = (bf16_t)fmaxf(s[q] + bb[q], 0.f);
  *(bf16x4*)(A2 + (size_t)b*1152 + j) = o;
}

__global__ __launch_bounds__(256) void reduce2_kernel(
    const float* __restrict__ P, const float* __restrict__ b3,
    const float* __restrict__ b4, float* __restrict__ out)
{
  const int t = blockIdx.x*256 + threadIdx.x;  // 147456 threads
  const int j4 = t << 2;
  const int b = j4 / 1152;
  const int j = j4 - b*1152;
  f32x4 s = {};
#pragma unroll
  for (int ss = 0; ss < 6; ++ss)
    s += *(const f32x4*)(P + ((size_t)ss*512 + (size_t)b)*1152 + j);
  f32x4 v3 = *(const f32x4*)(b3 + j);
  f32x4 v4 = *(const f32x4*)(b4 + j);
  f32x4 o;
#pragma unroll
  for (int q = 0; q < 4; ++q) o[q] = fmaxf(s[q] + v3[q] + v4[q], 0.f);
  *(f32x4*)(out + (size_t)b*1152 + j) = o;
}

// -------------------------------------------------------------------- launch
extern "C" void kernel_launch(void* const* d_in, const int* in_sizes, int n_in,
                              void* d_out, int out_size, void* d_ws, size_t ws_size,
                              hipStream_t stream) {
  const float* x  = (const float*)d_in[0];
  const float* l  = (const float*)d_in[1];
  const float* W1 = (const float*)d_in[2];
  const float* b1 = (const float*)d_in[3];
  const float* W2 = (const float*)d_in[4];
  const float* b2 = (const float*)d_in[5];
  const float* W3 = (const float*)d_in[6];
  const float* b3 = (const float*)d_in[7];
  const float* W4 = (const float*)d_in[8];
  const float* b4 = (const float*)d_in[9];
  float* out = (float*)d_out;
  char* ws = (char*)d_ws;
  bf16_t* W1bf = (bf16_t*)(ws + OFF_W1BF);
  bf16_t* B2   = (bf16_t*)(ws + OFF_B2);
  bf16_t* g    = (bf16_t*)(ws + OFF_G);
  bf16_t* A2   = (bf16_t*)(ws + OFF_A2);
  float*  P1   = (float*)(ws + OFF_P1);

  prep_kernel<<<2816, 256, 0, stream>>>(x, l, W1, W2, b2, W3, W4, g, W1bf, B2, A2);
  // h partials: M=512, N=1024, K=9216, split 16 -> 512 blocks, chunk 576 (9 iters)
  gemm_bt<16><<<4*8*16, 256, 0, stream>>>(g, 9216, W1bf, 9216, P1, 512, 1024, 9216);
  reduce1_kernel<<<512, 256, 0, stream>>>(P1, b1, A2);
  // out partials: M=512, N=1152, K=1152, split 6 -> 216 blocks, chunk 192 (3 iters)
  gemm_bt<6><<<4*9*6, 256, 0, stream>>>(A2, 1152, B2, 1152, P1, 512, 1152, 1152);
  reduce2_kernel<<<576, 256, 0, stream>>>(P1, b3, b4, out);
}